// Round 3
// baseline (272.126 us; speedup 1.0000x reference)
//
#include <hip/hip_runtime.h>
#include <hip/hip_bf16.h>

// B=4, S=1024, D=1024, H=16, d_k=64, MAX_REL=128 (NP=257)
#define NP 257

typedef __attribute__((ext_vector_type(8))) short short8;
typedef __attribute__((ext_vector_type(4))) float f32x4;

__device__ __forceinline__ unsigned short f32_to_bf16(float f) {
    unsigned int u = __float_as_uint(f);
    unsigned int r = (u + 0x7FFFu + ((u >> 16) & 1u)) >> 16;
    return (unsigned short)r;
}
__device__ __forceinline__ float bf16_to_f32(unsigned short u) {
    return __uint_as_float(((unsigned int)u) << 16);
}

// ---------------- fp32 -> bf16 pack, 8 elems/thread
__global__ __launch_bounds__(256) void cvt_bf16(const float* __restrict__ src,
                                                unsigned short* __restrict__ dst, int n8)
{
    int i = blockIdx.x * 256 + threadIdx.x;
    if (i >= n8) return;
    const float4* s = reinterpret_cast<const float4*>(src) + (size_t)i * 2;
    float4 a = s[0], b = s[1];
    union { unsigned short u[8]; uint4 v; } p;
    p.u[0] = f32_to_bf16(a.x); p.u[1] = f32_to_bf16(a.y);
    p.u[2] = f32_to_bf16(a.z); p.u[3] = f32_to_bf16(a.w);
    p.u[4] = f32_to_bf16(b.x); p.u[5] = f32_to_bf16(b.y);
    p.u[6] = f32_to_bf16(b.z); p.u[7] = f32_to_bf16(b.w);
    reinterpret_cast<uint4*>(dst)[i] = p.v;
}

// ---------------- MFMA projection: out[m,n] = sum_k X[m,k]*W[n,k] + bias[n]
// M=4096 N=1024 K=1024. Tile 64x64x64, 256 thr (4 waves, 2x2), bf16 in/out fp32 acc.
template <bool DUMMY>
__global__ __launch_bounds__(256) void proj_mfma(const unsigned short* __restrict__ Xb,
                                                 const unsigned short* __restrict__ Wb,
                                                 const float* __restrict__ bias,
                                                 unsigned short* __restrict__ outb)
{
    __shared__ unsigned short As[4096];   // 64 rows x 8 chunks x 8 bf16
    __shared__ unsigned short Bs[4096];
    const int tid = threadIdx.x;
    const int lane = tid & 63;
    const int w = tid >> 6;
    const int wi = w >> 1, wj = w & 1;
    const int bm = blockIdx.x * 64, bn = blockIdx.y * 64;

    f32x4 acc[2][2];
    #pragma unroll
    for (int i = 0; i < 2; ++i)
        #pragma unroll
        for (int j = 0; j < 2; ++j) acc[i][j] = (f32x4){0.f, 0.f, 0.f, 0.f};

    const int f0 = w * 64 + lane, f1 = f0 + 256;
    const int row0 = f0 >> 3, cl0 = (f0 & 7) ^ (row0 & 7);
    const int row1 = f1 >> 3, cl1 = (f1 & 7) ^ (row1 & 7);
    const size_t gaA0 = (size_t)(bm + row0) * 1024 + cl0 * 8;
    const size_t gaA1 = (size_t)(bm + row1) * 1024 + cl1 * 8;
    const size_t gaB0 = (size_t)(bn + row0) * 1024 + cl0 * 8;
    const size_t gaB1 = (size_t)(bn + row1) * 1024 + cl1 * 8;
    const int ldsA0 = w * 512, ldsA1 = 2048 + w * 512;

    const int r15 = lane & 15, g = lane >> 4;

    for (int kt = 0; kt < 16; ++kt) {
        const int k0 = kt * 64;
        __builtin_amdgcn_global_load_lds(
            (const __attribute__((address_space(1))) void*)(Xb + gaA0 + k0),
            (__attribute__((address_space(3))) void*)(As + ldsA0), 16, 0, 0);
        __builtin_amdgcn_global_load_lds(
            (const __attribute__((address_space(1))) void*)(Xb + gaA1 + k0),
            (__attribute__((address_space(3))) void*)(As + ldsA1), 16, 0, 0);
        __builtin_amdgcn_global_load_lds(
            (const __attribute__((address_space(1))) void*)(Wb + gaB0 + k0),
            (__attribute__((address_space(3))) void*)(Bs + ldsA0), 16, 0, 0);
        __builtin_amdgcn_global_load_lds(
            (const __attribute__((address_space(1))) void*)(Wb + gaB1 + k0),
            (__attribute__((address_space(3))) void*)(Bs + ldsA1), 16, 0, 0);
        __syncthreads();

        #pragma unroll
        for (int kk = 0; kk < 2; ++kk) {
            const int c = kk * 4 + g;
            const int ra = wi * 32 + r15, ra1 = ra + 16;
            const int rb = wj * 32 + r15, rb1 = rb + 16;
            short8 a0 = *(const short8*)&As[(ra  * 8 + (c ^ (ra  & 7))) * 8];
            short8 a1 = *(const short8*)&As[(ra1 * 8 + (c ^ (ra1 & 7))) * 8];
            short8 b0 = *(const short8*)&Bs[(rb  * 8 + (c ^ (rb  & 7))) * 8];
            short8 b1 = *(const short8*)&Bs[(rb1 * 8 + (c ^ (rb1 & 7))) * 8];
            acc[0][0] = __builtin_amdgcn_mfma_f32_16x16x32_bf16(a0, b0, acc[0][0], 0, 0, 0);
            acc[0][1] = __builtin_amdgcn_mfma_f32_16x16x32_bf16(a0, b1, acc[0][1], 0, 0, 0);
            acc[1][0] = __builtin_amdgcn_mfma_f32_16x16x32_bf16(a1, b0, acc[1][0], 0, 0, 0);
            acc[1][1] = __builtin_amdgcn_mfma_f32_16x16x32_bf16(a1, b1, acc[1][1], 0, 0, 0);
        }
        __syncthreads();
    }

    const int orow = bm + wi * 32 + (g << 2);
    const int ocol0 = bn + wj * 32 + r15;
    #pragma unroll
    for (int tj = 0; tj < 2; ++tj) {
        const int n = ocol0 + tj * 16;
        const float bv = bias[n];
        #pragma unroll
        for (int ti = 0; ti < 2; ++ti)
            #pragma unroll
            for (int r = 0; r < 4; ++r)
                outb[(size_t)(orow + ti * 16 + r) * 1024 + n] = f32_to_bf16(acc[ti][tj][r] + bv);
    }
}

// ---------------- q_mean from bf16 q
__global__ __launch_bounds__(256) void qmean_kernel(const unsigned short* __restrict__ qb,
                                                    float* __restrict__ qmean)
{
    int idx = blockIdx.x * 256 + threadIdx.x;   // 262144
    int d = idx & 63;
    size_t bs = (size_t)(idx >> 6);
    float s = 0.f;
    #pragma unroll
    for (int h = 0; h < 16; ++h) s += bf16_to_f32(qb[bs * 1024 + h * 64 + d]);
    qmean[idx] = s * 0.0625f;
}

// ---------------- rel_dot[b,i,p] = scale * dot(q_mean[b,i], rel_table[p])
__global__ __launch_bounds__(256) void reldot_kernel(const float* __restrict__ qmean,
                                                     const float* __restrict__ relk,
                                                     float* __restrict__ reldot)
{
    __shared__ __align__(16) float qm[64];
    const int bi = blockIdx.x;                  // 4096
    if (threadIdx.x < 64) qm[threadIdx.x] = qmean[(size_t)bi * 64 + threadIdx.x];
    __syncthreads();
    const float4* qm4 = reinterpret_cast<const float4*>(qm);
    for (int p = threadIdx.x; p < NP; p += 256) {
        const float4* rk4 = reinterpret_cast<const float4*>(relk + (size_t)p * 64);
        float s0 = 0.f, s1 = 0.f, s2 = 0.f, s3 = 0.f;
        #pragma unroll
        for (int d4 = 0; d4 < 16; ++d4) {
            float4 a = qm4[d4];
            float4 b = rk4[d4];
            s0 = fmaf(a.x, b.x, s0);
            s1 = fmaf(a.y, b.y, s1);
            s2 = fmaf(a.z, b.z, s2);
            s3 = fmaf(a.w, b.w, s3);
        }
        reldot[(size_t)bi * NP + p] = (s0 + s1 + s2 + s3) * 0.125f;
    }
}

// ---------------- MFMA attention, register-resident scores.
// Block: 16 q-rows x 1024 cols for one (b,h); wave w owns cols [256w, 256w+256).
// Scores live in s[16][4] VGPRs (16 tiles x f32x4). Softmax: per-lane reduce ->
// 16-lane shfl reduce -> 64-float LDS cross-wave combine. One exp per element.
__global__ __launch_bounds__(256) void attn_reg(const unsigned short* __restrict__ qb,
                                                const unsigned short* __restrict__ kb,
                                                const int* __restrict__ mask,
                                                const float* __restrict__ rdot,
                                                float* __restrict__ out)
{
    __shared__ float redmax[4][16];
    __shared__ float redsum[4][16];
    const int i0 = blockIdx.x * 16;
    const int h = blockIdx.y, b = blockIdx.z;
    const int tid = threadIdx.x, lane = tid & 63, w = tid >> 6;
    const int r15 = lane & 15, g = lane >> 4;
    const size_t qkbase = ((size_t)b << 20) + h * 64;

    // A frags: Q rows i0..i0+15
    short8 af0, af1;
    {
        const unsigned short* qp = qb + qkbase + (size_t)(i0 + r15) * 1024 + 8 * g;
        af0 = *(const short8*)(qp);
        af1 = *(const short8*)(qp + 32);
    }

    const int n0w = w * 256;
    const int irow = i0 + (g << 2);              // + r
    const size_t maskrow = ((size_t)(b * 1024 + irow)) << 10;   // + r<<10 + j
    const size_t rdrow = (size_t)(b * 1024 + irow) * NP;        // + r*NP

    float s[16][4];
    #pragma unroll
    for (int jt = 0; jt < 16; ++jt) {
        const int n0 = n0w + jt * 16;
        const unsigned short* kp = kb + qkbase + (size_t)(n0 + r15) * 1024 + 8 * g;
        short8 bf0 = *(const short8*)(kp);
        short8 bf1 = *(const short8*)(kp + 32);
        f32x4 acc = (f32x4){0.f, 0.f, 0.f, 0.f};
        acc = __builtin_amdgcn_mfma_f32_16x16x32_bf16(af0, bf0, acc, 0, 0, 0);
        acc = __builtin_amdgcn_mfma_f32_16x16x32_bf16(af1, bf1, acc, 0, 0, 0);
        const int j = n0 + r15;
        #pragma unroll
        for (int r = 0; r < 4; ++r) {
            int d = j - (irow + r);
            d = d < -128 ? -128 : (d > 128 ? 128 : d);
            float v = acc[r] * 0.125f + rdot[rdrow + r * NP + d + 128];
            if (mask[maskrow + ((size_t)r << 10) + j] == 0) v = -1e9f;
            s[jt][r] = v;
        }
    }

    // ---- row max: per-lane over 16 tiles, then 16-lane shuffle, then cross-wave
    float pm[4];
    #pragma unroll
    for (int r = 0; r < 4; ++r) {
        float m = s[0][r];
        #pragma unroll
        for (int jt = 1; jt < 16; ++jt) m = fmaxf(m, s[jt][r]);
        pm[r] = m;
    }
    #pragma unroll
    for (int off = 1; off < 16; off <<= 1)
        #pragma unroll
        for (int r = 0; r < 4; ++r) pm[r] = fmaxf(pm[r], __shfl_xor(pm[r], off, 64));
    if (r15 == 0) {
        #pragma unroll
        for (int r = 0; r < 4; ++r) redmax[w][(g << 2) + r] = pm[r];
    }
    __syncthreads();
    float m[4];
    #pragma unroll
    for (int r = 0; r < 4; ++r) {
        const int rr = (g << 2) + r;
        m[r] = fmaxf(fmaxf(redmax[0][rr], redmax[1][rr]),
                     fmaxf(redmax[2][rr], redmax[3][rr]));
    }

    // ---- exp in place + row sum
    float ps[4] = {0.f, 0.f, 0.f, 0.f};
    #pragma unroll
    for (int jt = 0; jt < 16; ++jt)
        #pragma unroll
        for (int r = 0; r < 4; ++r) {
            float e = __expf(s[jt][r] - m[r]);
            s[jt][r] = e;
            ps[r] += e;
        }
    #pragma unroll
    for (int off = 1; off < 16; off <<= 1)
        #pragma unroll
        for (int r = 0; r < 4; ++r) ps[r] += __shfl_xor(ps[r], off, 64);
    if (r15 == 0) {
        #pragma unroll
        for (int r = 0; r < 4; ++r) redsum[w][(g << 2) + r] = ps[r];
    }
    __syncthreads();
    float inv[4];
    #pragma unroll
    for (int r = 0; r < 4; ++r) {
        const int rr = (g << 2) + r;
        inv[r] = 1.0f / (redsum[0][rr] + redsum[1][rr] + redsum[2][rr] + redsum[3][rr]);
    }

    // ---- scale + store straight from registers
    float* ob = out + ((((size_t)((b * 16 + h) * 1024 + irow)) << 10) + n0w + r15);
    #pragma unroll
    for (int jt = 0; jt < 16; ++jt)
        #pragma unroll
        for (int r = 0; r < 4; ++r)
            ob[((size_t)r << 10) + jt * 16] = s[jt][r] * inv[r];
}

extern "C" void kernel_launch(void* const* d_in, const int* in_sizes, int n_in,
                              void* d_out, int out_size, void* d_ws, size_t ws_size,
                              hipStream_t stream) {
    const float* query = (const float*)d_in[0];
    const float* key   = (const float*)d_in[1];
    const int*   mask  = (const int*)d_in[2];
    const float* Wq    = (const float*)d_in[3];
    const float* bq    = (const float*)d_in[4];
    const float* Wk    = (const float*)d_in[5];
    const float* bk    = (const float*)d_in[6];
    const float* relk  = (const float*)d_in[7];

    char* ws = (char*)d_ws;
    unsigned short* qB     = (unsigned short*)(ws);                  // 8 MB  q bf16
    unsigned short* kB     = (unsigned short*)(ws + (8u  << 20));    // 8 MB  k bf16
    unsigned short* queryb = (unsigned short*)(ws + (16u << 20));    // 8 MB
    unsigned short* keyb   = (unsigned short*)(ws + (24u << 20));    // 8 MB
    unsigned short* Wqb    = (unsigned short*)(ws + (32u << 20));    // 2 MB
    unsigned short* Wkb    = (unsigned short*)(ws + (34u << 20));    // 2 MB
    float*          qmean  = (float*)(ws + (36u << 20));             // 1 MB
    float*          rdot   = (float*)(ws + (37u << 20));             // 4.21 MB
    float*          out    = (float*)d_out;

    cvt_bf16<<<2048, 256, 0, stream>>>(query, queryb, 524288);
    cvt_bf16<<<2048, 256, 0, stream>>>(key,   keyb,   524288);
    cvt_bf16<<<512,  256, 0, stream>>>(Wq,    Wqb,    131072);
    cvt_bf16<<<512,  256, 0, stream>>>(Wk,    Wkb,    131072);

    dim3 pg(64, 16);
    proj_mfma<false><<<pg, 256, 0, stream>>>(queryb, Wqb, bq, qB);
    proj_mfma<false><<<pg, 256, 0, stream>>>(keyb,   Wkb, bk, kB);

    qmean_kernel<<<1024, 256, 0, stream>>>(qB, qmean);
    reldot_kernel<<<4096, 256, 0, stream>>>(qmean, relk, rdot);

    attn_reg<<<dim3(64, 16, 4), 256, 0, stream>>>(qB, kB, mask, rdot, out);
}

// Round 4
// 207.736 us; speedup vs baseline: 1.3100x; 1.3100x over previous
//
#include <hip/hip_runtime.h>
#include <hip/hip_bf16.h>

// B=4, S=1024, D=1024, H=16, d_k=64, MAX_REL=128 (NP=257)
#define NP 257

typedef __attribute__((ext_vector_type(8))) short short8;
typedef __attribute__((ext_vector_type(4))) float f32x4;

__device__ __forceinline__ unsigned short f32_to_bf16(float f) {
    unsigned int u = __float_as_uint(f);
    unsigned int r = (u + 0x7FFFu + ((u >> 16) & 1u)) >> 16;
    return (unsigned short)r;
}
__device__ __forceinline__ float bf16_to_f32(unsigned short u) {
    return __uint_as_float(((unsigned int)u) << 16);
}

// ---------------- fp32 -> bf16 pack, 8 elems/thread
__global__ __launch_bounds__(256) void cvt_bf16(const float* __restrict__ src,
                                                unsigned short* __restrict__ dst, int n8)
{
    int i = blockIdx.x * 256 + threadIdx.x;
    if (i >= n8) return;
    const float4* s = reinterpret_cast<const float4*>(src) + (size_t)i * 2;
    float4 a = s[0], b = s[1];
    union { unsigned short u[8]; uint4 v; } p;
    p.u[0] = f32_to_bf16(a.x); p.u[1] = f32_to_bf16(a.y);
    p.u[2] = f32_to_bf16(a.z); p.u[3] = f32_to_bf16(a.w);
    p.u[4] = f32_to_bf16(b.x); p.u[5] = f32_to_bf16(b.y);
    p.u[6] = f32_to_bf16(b.z); p.u[7] = f32_to_bf16(b.w);
    reinterpret_cast<uint4*>(dst)[i] = p.v;
}

// ---------------- MFMA projection: out[m,n] = sum_k X[m,k]*W[n,k] + bias[n]
// M=4096 N=1024 K=1024. Tile 128x64x64, 256 thr (4 waves 2x2: wave tile 64x32).
__global__ __launch_bounds__(256) void proj_mfma(const unsigned short* __restrict__ Xb,
                                                 const unsigned short* __restrict__ Wb,
                                                 const float* __restrict__ bias,
                                                 unsigned short* __restrict__ outb)
{
    __shared__ unsigned short As[8192];   // 128 rows x 8 chunks x 8 bf16 (16 KB)
    __shared__ unsigned short Bs[4096];   // 64 rows x 8 chunks x 8 bf16 (8 KB)
    const int tid = threadIdx.x;
    const int lane = tid & 63;
    const int w = tid >> 6;
    const int wi = w >> 1, wj = w & 1;
    const int bm = blockIdx.x * 128, bn = blockIdx.y * 64;
    const int r15 = lane & 15, g = lane >> 4;

    f32x4 acc[4][2];
    #pragma unroll
    for (int i = 0; i < 4; ++i)
        #pragma unroll
        for (int j = 0; j < 2; ++j) acc[i][j] = (f32x4){0.f, 0.f, 0.f, 0.f};

    // staging: slot f = it*256 + tid (16B slots); row = f>>3, phys chunk f&7,
    // logical chunk = (f&7)^(row&7); LDS dest linear, source pre-swizzled.
    size_t offA[4], offB[2];
    #pragma unroll
    for (int it = 0; it < 4; ++it) {
        int f = it * 256 + tid, row = f >> 3, cl = (f & 7) ^ (row & 7);
        offA[it] = (size_t)(bm + row) * 1024 + cl * 8;
    }
    #pragma unroll
    for (int it = 0; it < 2; ++it) {
        int f = it * 256 + tid, row = f >> 3, cl = (f & 7) ^ (row & 7);
        offB[it] = (size_t)(bn + row) * 1024 + cl * 8;
    }

    for (int kt = 0; kt < 16; ++kt) {
        const int k0 = kt * 64;
        #pragma unroll
        for (int it = 0; it < 4; ++it)
            __builtin_amdgcn_global_load_lds(
                (const __attribute__((address_space(1))) void*)(Xb + offA[it] + k0),
                (__attribute__((address_space(3))) void*)(As + it * 2048 + w * 512), 16, 0, 0);
        #pragma unroll
        for (int it = 0; it < 2; ++it)
            __builtin_amdgcn_global_load_lds(
                (const __attribute__((address_space(1))) void*)(Wb + offB[it] + k0),
                (__attribute__((address_space(3))) void*)(Bs + it * 2048 + w * 512), 16, 0, 0);
        __syncthreads();

        #pragma unroll
        for (int kk = 0; kk < 2; ++kk) {
            const int c = kk * 4 + g;
            short8 a[4], bfr[2];
            #pragma unroll
            for (int ti = 0; ti < 4; ++ti) {
                const int ra = wi * 64 + ti * 16 + r15;
                a[ti] = *(const short8*)&As[(ra * 8 + (c ^ (ra & 7))) * 8];
            }
            #pragma unroll
            for (int tj = 0; tj < 2; ++tj) {
                const int rb = wj * 32 + tj * 16 + r15;
                bfr[tj] = *(const short8*)&Bs[(rb * 8 + (c ^ (rb & 7))) * 8];
            }
            #pragma unroll
            for (int ti = 0; ti < 4; ++ti)
                #pragma unroll
                for (int tj = 0; tj < 2; ++tj)
                    acc[ti][tj] = __builtin_amdgcn_mfma_f32_16x16x32_bf16(a[ti], bfr[tj], acc[ti][tj], 0, 0, 0);
        }
        __syncthreads();
    }

    // C/D: col = lane&15, row = (lane>>4)*4 + reg
    #pragma unroll
    for (int tj = 0; tj < 2; ++tj) {
        const int n = bn + wj * 32 + tj * 16 + r15;
        const float bv = bias[n];
        #pragma unroll
        for (int ti = 0; ti < 4; ++ti) {
            const int orow = bm + wi * 64 + ti * 16 + (g << 2);
            #pragma unroll
            for (int r = 0; r < 4; ++r)
                outb[(size_t)(orow + r) * 1024 + n] = f32_to_bf16(acc[ti][tj][r] + bv);
        }
    }
}

// ---------------- q_mean from bf16 q
__global__ __launch_bounds__(256) void qmean_kernel(const unsigned short* __restrict__ qb,
                                                    float* __restrict__ qmean)
{
    int idx = blockIdx.x * 256 + threadIdx.x;   // 262144
    int d = idx & 63;
    size_t bs = (size_t)(idx >> 6);
    float s = 0.f;
    #pragma unroll
    for (int h = 0; h < 16; ++h) s += bf16_to_f32(qb[bs * 1024 + h * 64 + d]);
    qmean[idx] = s * 0.0625f;
}

// ---------------- rel_dot[b,i,p] = scale * dot(q_mean[b,i], rel_table[p])
__global__ __launch_bounds__(256) void reldot_kernel(const float* __restrict__ qmean,
                                                     const float* __restrict__ relk,
                                                     float* __restrict__ reldot)
{
    __shared__ __align__(16) float qm[64];
    const int bi = blockIdx.x;                  // 4096
    if (threadIdx.x < 64) qm[threadIdx.x] = qmean[(size_t)bi * 64 + threadIdx.x];
    __syncthreads();
    const float4* qm4 = reinterpret_cast<const float4*>(qm);
    for (int p = threadIdx.x; p < NP; p += 256) {
        const float4* rk4 = reinterpret_cast<const float4*>(relk + (size_t)p * 64);
        float s0 = 0.f, s1 = 0.f, s2 = 0.f, s3 = 0.f;
        #pragma unroll
        for (int d4 = 0; d4 < 16; ++d4) {
            float4 a = qm4[d4];
            float4 b = rk4[d4];
            s0 = fmaf(a.x, b.x, s0);
            s1 = fmaf(a.y, b.y, s1);
            s2 = fmaf(a.z, b.z, s2);
            s3 = fmaf(a.w, b.w, s3);
        }
        reldot[(size_t)bi * NP + p] = (s0 + s1 + s2 + s3) * 0.125f;
    }
}

// ---------------- bias[b,i,j] = rdot[b,i,clip(j-i)+128] + (mask ? 0 : -1e9)
__global__ __launch_bounds__(256) void biask(const int* __restrict__ mask,
                                             const float* __restrict__ rdot,
                                             float* __restrict__ bias)
{
    const int idx = blockIdx.x * 256 + threadIdx.x;   // 1,048,576
    const int j0 = (idx & 255) * 4;
    const int i  = (idx >> 8) & 1023;
    const int b  = idx >> 18;
    const size_t row = (size_t)(b * 1024 + i);
    const int4 mk = reinterpret_cast<const int4*>(mask + (row << 10))[idx & 255];
    const float* rr = rdot + row * NP + 128;
    float4 v;
    int d;
    d = j0 + 0 - i; d = d < -128 ? -128 : (d > 128 ? 128 : d); v.x = mk.x ? rr[d] : -1e9f;
    d = j0 + 1 - i; d = d < -128 ? -128 : (d > 128 ? 128 : d); v.y = mk.y ? rr[d] : -1e9f;
    d = j0 + 2 - i; d = d < -128 ? -128 : (d > 128 ? 128 : d); v.z = mk.z ? rr[d] : -1e9f;
    d = j0 + 3 - i; d = d < -128 ? -128 : (d > 128 ? 128 : d); v.w = mk.w ? rr[d] : -1e9f;
    reinterpret_cast<float4*>(bias + (row << 10))[idx & 255] = v;
}

// ---------------- MFMA attention, fused exp, no max pass.
// Block: 16 q-rows x 1024 j for one (b,h); wave w owns j in [256w, 256w+256).
// Swapped mfma(K,Q): C col = q-row (lane&15), row = j (g*4+reg) -> lane holds
// 4 consecutive j of ONE row. exp fused into epilogue (scores bounded, masked
// bias=-1e9 -> exp=0), e stored bf16 in LDS (add-rotate swizzle), sum via
// 2 shfl_xor + cross-wave LDS. One exp per element; coalesced float4 output.
__global__ __launch_bounds__(256) void attn2(const unsigned short* __restrict__ qb,
                                             const unsigned short* __restrict__ kb,
                                             const float* __restrict__ bias,
                                             float* __restrict__ out)
{
    __shared__ unsigned short e_lds[16 * 1024];   // 32 KB
    __shared__ float redsum[4][16];
    const int i0 = blockIdx.x * 16;
    const int h = blockIdx.y, b = blockIdx.z;
    const int tid = threadIdx.x, lane = tid & 63, w = tid >> 6;
    const int r15 = lane & 15, g = lane >> 4;
    const size_t qkbase = ((size_t)b << 20) + h * 64;

    // B-operand: Q rows i0..i0+15 (fixed for whole block)
    short8 qf0, qf1;
    {
        const unsigned short* qp = qb + qkbase + (size_t)(i0 + r15) * 1024 + 8 * g;
        qf0 = *(const short8*)(qp);
        qf1 = *(const short8*)(qp + 32);
    }

    const int n0w = w * 256;
    const float* brow = bias + (((size_t)(b * 1024 + i0 + r15)) << 10);
    float ps = 0.f;

    #pragma unroll
    for (int jt = 0; jt < 16; ++jt) {
        const int j0 = n0w + jt * 16;
        const unsigned short* kp = kb + qkbase + (size_t)(j0 + r15) * 1024 + 8 * g;
        short8 kf0 = *(const short8*)(kp);
        short8 kf1 = *(const short8*)(kp + 32);
        f32x4 acc = (f32x4){0.f, 0.f, 0.f, 0.f};
        acc = __builtin_amdgcn_mfma_f32_16x16x32_bf16(kf0, qf0, acc, 0, 0, 0);
        acc = __builtin_amdgcn_mfma_f32_16x16x32_bf16(kf1, qf1, acc, 0, 0, 0);
        const int jc = j0 + (g << 2);                 // first of this lane's 4 cols
        float4 bv = *reinterpret_cast<const float4*>(brow + jc);
        float e0 = __expf(fmaf(acc[0], 0.125f, bv.x));
        float e1 = __expf(fmaf(acc[1], 0.125f, bv.y));
        float e2 = __expf(fmaf(acc[2], 0.125f, bv.z));
        float e3 = __expf(fmaf(acc[3], 0.125f, bv.w));
        ps += (e0 + e1) + (e2 + e3);
        unsigned int u0 = f32_to_bf16(e0) | ((unsigned int)f32_to_bf16(e1) << 16);
        unsigned int u1 = f32_to_bf16(e2) | ((unsigned int)f32_to_bf16(e3) << 16);
        // add-rotate swizzle: col' = (col + row*4) & 1023  (keeps 4-ushort align)
        const int us = r15 * 1024 + ((jc + r15 * 4) & 1023);
        *reinterpret_cast<uint2*>(&e_lds[us]) = make_uint2(u0, u1);
    }

    // row sum: lanes {r15, r15+16, r15+32, r15+48} hold the same row
    ps += __shfl_xor(ps, 16, 64);
    ps += __shfl_xor(ps, 32, 64);
    if (lane < 16) redsum[w][r15] = ps;
    __syncthreads();

    // output: wave w -> rows 4w..4w+3, coalesced float4 stores
    #pragma unroll
    for (int rr = 0; rr < 4; ++rr) {
        const int li = w * 4 + rr;
        const float inv = 1.0f / (redsum[0][li] + redsum[1][li] + redsum[2][li] + redsum[3][li]);
        float* op = out + (((size_t)((b * 16 + h) * 1024 + i0 + li)) << 10);
        #pragma unroll
        for (int n = 0; n < 4; ++n) {
            const int c = n * 256 + lane * 4;
            const int us = li * 1024 + ((c + li * 4) & 1023);
            uint2 u = *reinterpret_cast<const uint2*>(&e_lds[us]);
            float4 v;
            v.x = bf16_to_f32((unsigned short)(u.x & 0xFFFFu)) * inv;
            v.y = bf16_to_f32((unsigned short)(u.x >> 16)) * inv;
            v.z = bf16_to_f32((unsigned short)(u.y & 0xFFFFu)) * inv;
            v.w = bf16_to_f32((unsigned short)(u.y >> 16)) * inv;
            *reinterpret_cast<float4*>(op + c) = v;
        }
    }
}

extern "C" void kernel_launch(void* const* d_in, const int* in_sizes, int n_in,
                              void* d_out, int out_size, void* d_ws, size_t ws_size,
                              hipStream_t stream) {
    const float* query = (const float*)d_in[0];
    const float* key   = (const float*)d_in[1];
    const int*   mask  = (const int*)d_in[2];
    const float* Wq    = (const float*)d_in[3];
    const float* bq    = (const float*)d_in[4];
    const float* Wk    = (const float*)d_in[5];
    const float* bk    = (const float*)d_in[6];
    const float* relk  = (const float*)d_in[7];

    char* ws = (char*)d_ws;
    unsigned short* qB     = (unsigned short*)(ws);                  // 8 MB  q bf16
    unsigned short* kB     = (unsigned short*)(ws + (8u  << 20));    // 8 MB  k bf16
    unsigned short* queryb = (unsigned short*)(ws + (16u << 20));    // 8 MB (dead after proj q)
    unsigned short* keyb   = (unsigned short*)(ws + (24u << 20));    // 8 MB (dead after proj k)
    unsigned short* Wqb    = (unsigned short*)(ws + (32u << 20));    // 2 MB
    unsigned short* Wkb    = (unsigned short*)(ws + (34u << 20));    // 2 MB
    float*          qmean  = (float*)(ws + (36u << 20));             // 1 MB
    float*          rdot   = (float*)(ws + (37u << 20));             // 4.21 MB
    float*          biasA  = (float*)(ws + (16u << 20));             // 16 MB, overlays queryb+keyb
    float*          out    = (float*)d_out;

    cvt_bf16<<<2048, 256, 0, stream>>>(query, queryb, 524288);
    cvt_bf16<<<2048, 256, 0, stream>>>(key,   keyb,   524288);
    cvt_bf16<<<512,  256, 0, stream>>>(Wq,    Wqb,    131072);
    cvt_bf16<<<512,  256, 0, stream>>>(Wk,    Wkb,    131072);

    dim3 pg(32, 16);   // M/128, N/64
    proj_mfma<<<pg, 256, 0, stream>>>(queryb, Wqb, bq, qB);
    proj_mfma<<<pg, 256, 0, stream>>>(keyb,   Wkb, bk, kB);

    qmean_kernel<<<1024, 256, 0, stream>>>(qB, qmean);
    reldot_kernel<<<4096, 256, 0, stream>>>(qmean, relk, rdot);
    biask<<<4096, 256, 0, stream>>>(mask, rdot, biasA);

    attn2<<<dim3(64, 16, 4), 256, 0, stream>>>(qB, kB, biasA, out);
}

// Round 5
// 195.017 us; speedup vs baseline: 1.3954x; 1.0652x over previous
//
#include <hip/hip_runtime.h>
#include <hip/hip_bf16.h>

// B=4, S=1024, D=1024, H=16, d_k=64, MAX_REL=128 (NP=257)
#define NP 257

typedef __attribute__((ext_vector_type(8))) short short8;
typedef __attribute__((ext_vector_type(4))) float f32x4;

__device__ __forceinline__ unsigned short f32_to_bf16(float f) {
    unsigned int u = __float_as_uint(f);
    unsigned int r = (u + 0x7FFFu + ((u >> 16) & 1u)) >> 16;
    return (unsigned short)r;
}
__device__ __forceinline__ float bf16_to_f32(unsigned short u) {
    return __uint_as_float(((unsigned int)u) << 16);
}

// ---------------- fp32 -> bf16 pack, 8 elems/thread; grid.y selects buffer pair
__global__ __launch_bounds__(256) void cvt_bf16_2(const float* __restrict__ s0,
                                                  unsigned short* __restrict__ d0,
                                                  const float* __restrict__ s1,
                                                  unsigned short* __restrict__ d1,
                                                  int n8)
{
    int i = blockIdx.x * 256 + threadIdx.x;
    if (i >= n8) return;
    const float* src = blockIdx.y ? s1 : s0;
    unsigned short* dst = blockIdx.y ? d1 : d0;
    const float4* s = reinterpret_cast<const float4*>(src) + (size_t)i * 2;
    float4 a = s[0], b = s[1];
    union { unsigned short u[8]; uint4 v; } p;
    p.u[0] = f32_to_bf16(a.x); p.u[1] = f32_to_bf16(a.y);
    p.u[2] = f32_to_bf16(a.z); p.u[3] = f32_to_bf16(a.w);
    p.u[4] = f32_to_bf16(b.x); p.u[5] = f32_to_bf16(b.y);
    p.u[6] = f32_to_bf16(b.z); p.u[7] = f32_to_bf16(b.w);
    reinterpret_cast<uint4*>(dst)[i] = p.v;
}

// ---------------- MFMA projection, both GEMMs in one dispatch (blockIdx.z).
// out[m,n] = sum_k X[m,k]*W[n,k] + bias[n].  M=4096 N=1024 K=1024.
// Tile 128x128x64, 256 thr = 4 waves (2x2), wave tile 64x64 (4x4 frags).
// Per K-step: 8 global_load_lds(16B) stage, 16 ds_read_b128, 32 MFMA.
__global__ __launch_bounds__(256) void proj_mfma(const unsigned short* __restrict__ Xq,
                                                 const unsigned short* __restrict__ Wqb,
                                                 const float* __restrict__ bq,
                                                 unsigned short* __restrict__ outq,
                                                 const unsigned short* __restrict__ Xk,
                                                 const unsigned short* __restrict__ Wkb,
                                                 const float* __restrict__ bk,
                                                 unsigned short* __restrict__ outk)
{
    __shared__ unsigned short As[8192];   // 128 rows x 8 chunks x 8 bf16 (16 KB)
    __shared__ unsigned short Bs[8192];
    const unsigned short* Xb = blockIdx.z ? Xk : Xq;
    const unsigned short* Wb = blockIdx.z ? Wkb : Wqb;
    const float* bias        = blockIdx.z ? bk : bq;
    unsigned short* outb     = blockIdx.z ? outk : outq;

    const int tid = threadIdx.x;
    const int lane = tid & 63;
    const int w = tid >> 6;
    const int wi = w >> 1, wj = w & 1;
    const int bm = blockIdx.x * 128, bn = blockIdx.y * 128;
    const int r15 = lane & 15, g = lane >> 4;

    f32x4 acc[4][4];
    #pragma unroll
    for (int i = 0; i < 4; ++i)
        #pragma unroll
        for (int j = 0; j < 4; ++j) acc[i][j] = (f32x4){0.f, 0.f, 0.f, 0.f};

    // staging: 16B slot f = it*256 + tid; row = f>>3, phys chunk = f&7,
    // logical chunk = (f&7)^(row&7). LDS dest linear; source pre-swizzled (G21).
    size_t offA[4], offB[4];
    #pragma unroll
    for (int it = 0; it < 4; ++it) {
        int f = it * 256 + tid, row = f >> 3, cl = (f & 7) ^ (row & 7);
        offA[it] = (size_t)(bm + row) * 1024 + cl * 8;
        offB[it] = (size_t)(bn + row) * 1024 + cl * 8;
    }
    const int ldsbase = w * 512;   // ushort offset of this wave's slot group

    for (int kt = 0; kt < 16; ++kt) {
        const int k0 = kt * 64;
        #pragma unroll
        for (int it = 0; it < 4; ++it)
            __builtin_amdgcn_global_load_lds(
                (const __attribute__((address_space(1))) void*)(Xb + offA[it] + k0),
                (__attribute__((address_space(3))) void*)(As + it * 2048 + ldsbase), 16, 0, 0);
        #pragma unroll
        for (int it = 0; it < 4; ++it)
            __builtin_amdgcn_global_load_lds(
                (const __attribute__((address_space(1))) void*)(Wb + offB[it] + k0),
                (__attribute__((address_space(3))) void*)(Bs + it * 2048 + ldsbase), 16, 0, 0);
        __syncthreads();

        #pragma unroll
        for (int kk = 0; kk < 2; ++kk) {
            const int c = kk * 4 + g;
            short8 a[4], bfr[4];
            #pragma unroll
            for (int ti = 0; ti < 4; ++ti) {
                const int ra = wi * 64 + ti * 16 + r15;
                a[ti] = *(const short8*)&As[(ra * 8 + (c ^ (ra & 7))) * 8];
            }
            #pragma unroll
            for (int tj = 0; tj < 4; ++tj) {
                const int rb = wj * 64 + tj * 16 + r15;
                bfr[tj] = *(const short8*)&Bs[(rb * 8 + (c ^ (rb & 7))) * 8];
            }
            #pragma unroll
            for (int ti = 0; ti < 4; ++ti)
                #pragma unroll
                for (int tj = 0; tj < 4; ++tj)
                    acc[ti][tj] = __builtin_amdgcn_mfma_f32_16x16x32_bf16(a[ti], bfr[tj], acc[ti][tj], 0, 0, 0);
        }
        __syncthreads();
    }

    // C/D: col = lane&15, row = (lane>>4)*4 + reg
    #pragma unroll
    for (int tj = 0; tj < 4; ++tj) {
        const int n = bn + wj * 64 + tj * 16 + r15;
        const float bv = bias[n];
        #pragma unroll
        for (int ti = 0; ti < 4; ++ti) {
            const int orow = bm + wi * 64 + ti * 16 + (g << 2);
            #pragma unroll
            for (int r = 0; r < 4; ++r)
                outb[(size_t)(orow + r) * 1024 + n] = f32_to_bf16(acc[ti][tj][r] + bv);
        }
    }
}

// ---------------- q_mean from bf16 q
__global__ __launch_bounds__(256) void qmean_kernel(const unsigned short* __restrict__ qb,
                                                    float* __restrict__ qmean)
{
    int idx = blockIdx.x * 256 + threadIdx.x;   // 262144
    int d = idx & 63;
    size_t bs = (size_t)(idx >> 6);
    float s = 0.f;
    #pragma unroll
    for (int h = 0; h < 16; ++h) s += bf16_to_f32(qb[bs * 1024 + h * 64 + d]);
    qmean[idx] = s * 0.0625f;
}

// ---------------- rel_dot[b,i,p] = scale * dot(q_mean[b,i], rel_table[p])
__global__ __launch_bounds__(256) void reldot_kernel(const float* __restrict__ qmean,
                                                     const float* __restrict__ relk,
                                                     float* __restrict__ reldot)
{
    __shared__ __align__(16) float qm[64];
    const int bi = blockIdx.x;                  // 4096
    if (threadIdx.x < 64) qm[threadIdx.x] = qmean[(size_t)bi * 64 + threadIdx.x];
    __syncthreads();
    const float4* qm4 = reinterpret_cast<const float4*>(qm);
    for (int p = threadIdx.x; p < NP; p += 256) {
        const float4* rk4 = reinterpret_cast<const float4*>(relk + (size_t)p * 64);
        float s0 = 0.f, s1 = 0.f, s2 = 0.f, s3 = 0.f;
        #pragma unroll
        for (int d4 = 0; d4 < 16; ++d4) {
            float4 a = qm4[d4];
            float4 b = rk4[d4];
            s0 = fmaf(a.x, b.x, s0);
            s1 = fmaf(a.y, b.y, s1);
            s2 = fmaf(a.z, b.z, s2);
            s3 = fmaf(a.w, b.w, s3);
        }
        reldot[(size_t)bi * NP + p] = (s0 + s1 + s2 + s3) * 0.125f;
    }
}

// ---------------- bias[b,i,j] = rdot[b,i,clip(j-i)+128] + (mask ? 0 : -1e9)
__global__ __launch_bounds__(256) void biask(const int* __restrict__ mask,
                                             const float* __restrict__ rdot,
                                             float* __restrict__ bias)
{
    const int idx = blockIdx.x * 256 + threadIdx.x;   // 1,048,576
    const int j0 = (idx & 255) * 4;
    const int i  = (idx >> 8) & 1023;
    const int b  = idx >> 18;
    const size_t row = (size_t)(b * 1024 + i);
    const int4 mk = reinterpret_cast<const int4*>(mask + (row << 10))[idx & 255];
    const float* rr = rdot + row * NP + 128;
    float4 v;
    int d;
    d = j0 + 0 - i; d = d < -128 ? -128 : (d > 128 ? 128 : d); v.x = mk.x ? rr[d] : -1e9f;
    d = j0 + 1 - i; d = d < -128 ? -128 : (d > 128 ? 128 : d); v.y = mk.y ? rr[d] : -1e9f;
    d = j0 + 2 - i; d = d < -128 ? -128 : (d > 128 ? 128 : d); v.z = mk.z ? rr[d] : -1e9f;
    d = j0 + 3 - i; d = d < -128 ? -128 : (d > 128 ? 128 : d); v.w = mk.w ? rr[d] : -1e9f;
    reinterpret_cast<float4*>(bias + (row << 10))[idx & 255] = v;
}

// ---------------- MFMA attention, fused exp, no max pass (scores bounded).
__global__ __launch_bounds__(256) void attn2(const unsigned short* __restrict__ qb,
                                             const unsigned short* __restrict__ kb,
                                             const float* __restrict__ bias,
                                             float* __restrict__ out)
{
    __shared__ unsigned short e_lds[16 * 1024];   // 32 KB
    __shared__ float redsum[4][16];
    const int i0 = blockIdx.x * 16;
    const int h = blockIdx.y, b = blockIdx.z;
    const int tid = threadIdx.x, lane = tid & 63, w = tid >> 6;
    const int r15 = lane & 15, g = lane >> 4;
    const size_t qkbase = ((size_t)b << 20) + h * 64;

    short8 qf0, qf1;
    {
        const unsigned short* qp = qb + qkbase + (size_t)(i0 + r15) * 1024 + 8 * g;
        qf0 = *(const short8*)(qp);
        qf1 = *(const short8*)(qp + 32);
    }

    const int n0w = w * 256;
    const float* brow = bias + (((size_t)(b * 1024 + i0 + r15)) << 10);
    float ps = 0.f;

    #pragma unroll
    for (int jt = 0; jt < 16; ++jt) {
        const int j0 = n0w + jt * 16;
        const unsigned short* kp = kb + qkbase + (size_t)(j0 + r15) * 1024 + 8 * g;
        short8 kf0 = *(const short8*)(kp);
        short8 kf1 = *(const short8*)(kp + 32);
        f32x4 acc = (f32x4){0.f, 0.f, 0.f, 0.f};
        acc = __builtin_amdgcn_mfma_f32_16x16x32_bf16(kf0, qf0, acc, 0, 0, 0);
        acc = __builtin_amdgcn_mfma_f32_16x16x32_bf16(kf1, qf1, acc, 0, 0, 0);
        const int jc = j0 + (g << 2);
        float4 bv = *reinterpret_cast<const float4*>(brow + jc);
        float e0 = __expf(fmaf(acc[0], 0.125f, bv.x));
        float e1 = __expf(fmaf(acc[1], 0.125f, bv.y));
        float e2 = __expf(fmaf(acc[2], 0.125f, bv.z));
        float e3 = __expf(fmaf(acc[3], 0.125f, bv.w));
        ps += (e0 + e1) + (e2 + e3);
        unsigned int u0 = f32_to_bf16(e0) | ((unsigned int)f32_to_bf16(e1) << 16);
        unsigned int u1 = f32_to_bf16(e2) | ((unsigned int)f32_to_bf16(e3) << 16);
        const int us = r15 * 1024 + ((jc + r15 * 4) & 1023);
        *reinterpret_cast<uint2*>(&e_lds[us]) = make_uint2(u0, u1);
    }

    ps += __shfl_xor(ps, 16, 64);
    ps += __shfl_xor(ps, 32, 64);
    if (lane < 16) redsum[w][r15] = ps;
    __syncthreads();

    #pragma unroll
    for (int rr = 0; rr < 4; ++rr) {
        const int li = w * 4 + rr;
        const float inv = 1.0f / (redsum[0][li] + redsum[1][li] + redsum[2][li] + redsum[3][li]);
        float* op = out + (((size_t)((b * 16 + h) * 1024 + i0 + li)) << 10);
        #pragma unroll
        for (int n = 0; n < 4; ++n) {
            const int c = n * 256 + lane * 4;
            const int us = li * 1024 + ((c + li * 4) & 1023);
            uint2 u = *reinterpret_cast<const uint2*>(&e_lds[us]);
            float4 v;
            v.x = bf16_to_f32((unsigned short)(u.x & 0xFFFFu)) * inv;
            v.y = bf16_to_f32((unsigned short)(u.x >> 16)) * inv;
            v.z = bf16_to_f32((unsigned short)(u.y & 0xFFFFu)) * inv;
            v.w = bf16_to_f32((unsigned short)(u.y >> 16)) * inv;
            *reinterpret_cast<float4*>(op + c) = v;
        }
    }
}

extern "C" void kernel_launch(void* const* d_in, const int* in_sizes, int n_in,
                              void* d_out, int out_size, void* d_ws, size_t ws_size,
                              hipStream_t stream) {
    const float* query = (const float*)d_in[0];
    const float* key   = (const float*)d_in[1];
    const int*   mask  = (const int*)d_in[2];
    const float* Wq    = (const float*)d_in[3];
    const float* bq    = (const float*)d_in[4];
    const float* Wk    = (const float*)d_in[5];
    const float* bk    = (const float*)d_in[6];
    const float* relk  = (const float*)d_in[7];

    char* ws = (char*)d_ws;
    unsigned short* qB     = (unsigned short*)(ws);                  // 8 MB  q bf16
    unsigned short* kB     = (unsigned short*)(ws + (8u  << 20));    // 8 MB  k bf16
    unsigned short* queryb = (unsigned short*)(ws + (16u << 20));    // 8 MB (dead after proj)
    unsigned short* keyb   = (unsigned short*)(ws + (24u << 20));    // 8 MB (dead after proj)
    unsigned short* Wqb    = (unsigned short*)(ws + (32u << 20));    // 2 MB
    unsigned short* Wkb    = (unsigned short*)(ws + (34u << 20));    // 2 MB
    float*          qmean  = (float*)(ws + (36u << 20));             // 1 MB
    float*          rdot   = (float*)(ws + (37u << 20));             // 4.21 MB
    float*          biasA  = (float*)(ws + (16u << 20));             // 16 MB, overlays queryb+keyb
    float*          out    = (float*)d_out;

    cvt_bf16_2<<<dim3(2048, 2), 256, 0, stream>>>(query, queryb, key, keyb, 524288);
    cvt_bf16_2<<<dim3(512, 2),  256, 0, stream>>>(Wq, Wqb, Wk, Wkb, 131072);

    proj_mfma<<<dim3(32, 8, 2), 256, 0, stream>>>(queryb, Wqb, bq, qB,
                                                  keyb,   Wkb, bk, kB);

    qmean_kernel<<<1024, 256, 0, stream>>>(qB, qmean);
    reldot_kernel<<<4096, 256, 0, stream>>>(qmean, relk, rdot);
    biask<<<4096, 256, 0, stream>>>(mask, rdot, biasA);

    attn2<<<dim3(64, 16, 4), 256, 0, stream>>>(qB, kB, biasA, out);
}